// Round 1
// baseline (509.824 us; speedup 1.0000x reference)
//
#include <hip/hip_runtime.h>
#include <hip/hip_bf16.h>
#include <cstdint>
#include <cstddef>

typedef __bf16 bf16_t;
typedef bf16_t bf16x8 __attribute__((ext_vector_type(8)));
typedef float  f32x4  __attribute__((ext_vector_type(4)));

#define FWHT_N 4096

// ---- GEMM geometry: 256x256 tile, K-step 32, 4-deep LDS pipeline ----
#define BM 256
#define BN 256
#define KSTEP 32
#define ABYTES 16384          // 256 rows x 32 k x 2B (one step's A)
#define BUFBYTES 32768        // A + B per step-buffer
#define NBUF 4                // 4 x 32 KiB = 128 KiB LDS

// ---------------------------------------------------------------------------
// 16-point in-register FWHT (4 radix-2 stages, unnormalized)
// ---------------------------------------------------------------------------
__device__ __forceinline__ void fwht16(float v[16]) {
#pragma unroll
    for (int h = 1; h < 16; h <<= 1) {
#pragma unroll
        for (int i = 0; i < 16; ++i) {
            if (!(i & h)) {
                const float a = v[i];
                const float b = v[i | h];
                v[i]     = a + b;
                v[i | h] = a - b;
            }
        }
    }
}

// padded LDS address: +1 word every 32 => all round patterns are 2-way (free)
__device__ __forceinline__ int pad(int i) { return i + (i >> 5); }

// ---------------------------------------------------------------------------
// Kernel 1: normalized FWHT along rows of W, emit bf16 W'
// W' = H * W[o,:] / 64  (H symmetric => x@W'^T == fwht(x)@W^T)
// ---------------------------------------------------------------------------
__global__ __launch_bounds__(256) void fwht_rows_bf16(const float* __restrict__ W,
                                                      bf16_t* __restrict__ Wt) {
    __shared__ float lds[FWHT_N + (FWHT_N >> 5)];
    const int r = blockIdx.x;
    const int t = threadIdx.x;

    float v[16];

    // ---- round 0: bits 0-3, i = 16t + k (contiguous) ----
    const float4* src = (const float4*)(W + (size_t)r * FWHT_N + 16 * t);
    {
        const float4 a0 = src[0], a1 = src[1], a2 = src[2], a3 = src[3];
        v[0] = a0.x; v[1] = a0.y; v[2]  = a0.z; v[3]  = a0.w;
        v[4] = a1.x; v[5] = a1.y; v[6]  = a1.z; v[7]  = a1.w;
        v[8] = a2.x; v[9] = a2.y; v[10] = a2.z; v[11] = a2.w;
        v[12] = a3.x; v[13] = a3.y; v[14] = a3.z; v[15] = a3.w;
    }
    fwht16(v);
    {
        const int base = 16 * t + (t >> 1);
#pragma unroll
        for (int k = 0; k < 16; ++k) lds[base + k] = v[k];
    }
    __syncthreads();

    // ---- round 1: bits 4-7 ----
    const int b1 = ((t >> 4) << 8) | (t & 15);
#pragma unroll
    for (int k = 0; k < 16; ++k) v[k] = lds[pad(b1 + (k << 4))];
    fwht16(v);
#pragma unroll
    for (int k = 0; k < 16; ++k) lds[pad(b1 + (k << 4))] = v[k];
    __syncthreads();

    // ---- round 2: bits 8-11 ----
#pragma unroll
    for (int k = 0; k < 16; ++k) v[k] = lds[pad(t + (k << 8))];
    fwht16(v);

    const float s = 0.015625f;  // 1/sqrt(4096)
    bf16_t* dst = Wt + (size_t)r * FWHT_N + t;
#pragma unroll
    for (int k = 0; k < 16; ++k) dst[k << 8] = (bf16_t)(v[k] * s);
}

// ---------------------------------------------------------------------------
// Kernel 2: x fp32 -> bf16, 16B/lane stores
// ---------------------------------------------------------------------------
__global__ __launch_bounds__(256) void cvt_f32_bf16(const float4* __restrict__ x,
                                                    bf16x8* __restrict__ y) {
    const size_t i = (size_t)blockIdx.x * 256 + threadIdx.x;
    const float4 a = x[2 * i];
    const float4 b = x[2 * i + 1];
    bf16x8 o;
    o[0] = (bf16_t)a.x; o[1] = (bf16_t)a.y; o[2] = (bf16_t)a.z; o[3] = (bf16_t)a.w;
    o[4] = (bf16_t)b.x; o[5] = (bf16_t)b.y; o[6] = (bf16_t)b.z; o[7] = (bf16_t)b.w;
    y[i] = o;
}

// ---------------------------------------------------------------------------
// Kernel 3: C[M,N] = A[M,K] * B[N,K]^T + bias   (bf16 in, fp32 out)
// 256x256 tile, 8 waves (2Mx4N), KSTEP=32, 4-deep rotating LDS pipeline:
//   - stage step s+2 (global_load_lds x4) while computing step s
//   - counted s_waitcnt vmcnt(4) + raw s_barrier per step (never drain to 0)
//   - LDS swizzle: 16B k-block index XOR row bits 1-2 (conflict-free b128 reads)
//     applied on the pre-swizzled GLOBAL source (linear global_load_lds dest)
//   - s_setprio around the 32-MFMA cluster
// ---------------------------------------------------------------------------
__device__ __forceinline__ void g2lds16(const bf16_t* g, bf16_t* l) {
    __builtin_amdgcn_global_load_lds((__attribute__((address_space(1))) void*)g,
                                     (__attribute__((address_space(3))) void*)l,
                                     16, 0, 0);
}

__global__ __launch_bounds__(512, 2) void gemm256_bt_bias(
    const bf16_t* __restrict__ A,
    const bf16_t* __restrict__ Bm,
    const float* __restrict__ bias,
    float* __restrict__ C,
    int M, int N, int K)
{
    __shared__ __align__(16) char lds[NBUF * BUFBYTES];  // 128 KiB

    const int tid  = threadIdx.x;
    const int wave = tid >> 6;
    const int lane = tid & 63;
    const int quad = lane >> 4;
    const int l16  = lane & 15;

    const int m0 = blockIdx.y * BM;
    const int n0 = blockIdx.x * BN;
    const int wm = (wave >> 2) * 128;   // 2 M-warps
    const int wn = (wave & 3) * 64;     // 4 N-warps

    // ---- staging map: linear LDS dest <- inverse-swizzled global source ----
    // LDS element (row,k): byte = (row>>4)*1024 + (row&15)*64 + (2k ^ swz(row))
    // swz(row) = ((row>>1)&3)<<4  (16B-block XOR; keeps 16B loads contiguous)
    const int srow = wave * 16 + (lane >> 2);                      // 0..127
    const int scb  = (((lane & 3) ^ ((lane >> 3) & 3)) << 4);      // bytes in 64B k-run
    const int L0   = wave * 1024 + lane * 16;                      // linear LDS bytes, j=0

    const bf16_t* gA0 = A  + (size_t)(m0 + srow)       * K + (scb >> 1);
    const bf16_t* gA1 = A  + (size_t)(m0 + srow + 128) * K + (scb >> 1);
    const bf16_t* gB0 = Bm + (size_t)(n0 + srow)       * K + (scb >> 1);
    const bf16_t* gB1 = Bm + (size_t)(n0 + srow + 128) * K + (scb >> 1);

    // ---- ds_read fragment addresses (same swizzle on the read side) ----
    const int cbr   = ((quad ^ ((lane >> 1) & 3)) << 4);
    const int aoff  = l16 * 64 + cbr;
    const int abase = ((wm >> 4) << 10) + aoff;            // + mi*1024
    const int bbase = ABYTES + ((wn >> 4) << 10) + aoff;   // + ni*1024

    f32x4 acc[8][4] = {};

    const int NT = K / KSTEP;  // 128

    auto stage = [&](int s) {
        char* d = &lds[(s & (NBUF - 1)) * BUFBYTES];
        const int ko = s * KSTEP;
        g2lds16(gA0 + ko, (bf16_t*)(d + L0));
        g2lds16(gA1 + ko, (bf16_t*)(d + L0 + 8192));
        g2lds16(gB0 + ko, (bf16_t*)(d + ABYTES + L0));
        g2lds16(gB1 + ko, (bf16_t*)(d + ABYTES + L0 + 8192));
    };

    // prologue: steps 0 and 1 in flight; wait for step 0 (leave 1 in flight)
    stage(0);
    stage(1);
    asm volatile("s_waitcnt vmcnt(4)" ::: "memory");
    __builtin_amdgcn_s_barrier();
    __builtin_amdgcn_sched_barrier(0);

#pragma unroll 2
    for (int s = 0; s < NT; ++s) {
        if (s + 2 < NT) stage(s + 2);   // writes buf[(s+2)&3] = buf[(s-2)&3]: readers done 2 barriers ago

        const char* buf = &lds[(s & (NBUF - 1)) * BUFBYTES];
        bf16x8 bfr[4], af[8];
#pragma unroll
        for (int ni = 0; ni < 4; ++ni)
            bfr[ni] = *(const bf16x8*)(buf + bbase + (ni << 10));
#pragma unroll
        for (int mi = 0; mi < 8; ++mi)
            af[mi] = *(const bf16x8*)(buf + abase + (mi << 10));

        __builtin_amdgcn_s_setprio(1);
#pragma unroll
        for (int mi = 0; mi < 8; ++mi)
#pragma unroll
            for (int ni = 0; ni < 4; ++ni)
                acc[mi][ni] = __builtin_amdgcn_mfma_f32_16x16x32_bf16(
                    af[mi], bfr[ni], acc[mi][ni], 0, 0, 0);
        __builtin_amdgcn_s_setprio(0);

        if (s + 1 < NT) {
            // retire step s+1's 4 loads; keep step s+2's 4 in flight
            if (s + 2 < NT) { asm volatile("s_waitcnt vmcnt(4)" ::: "memory"); }
            else            { asm volatile("s_waitcnt vmcnt(0)" ::: "memory"); }
            __builtin_amdgcn_s_barrier();
            __builtin_amdgcn_sched_barrier(0);
        }
    }

    // ---- epilogue: C = acc + bias (C/D map: col=lane&15, row=quad*4+r) ----
    const int crow = quad * 4;
#pragma unroll
    for (int ni = 0; ni < 4; ++ni) {
        const int n  = n0 + wn + ni * 16 + l16;
        const float bv = bias[n];
#pragma unroll
        for (int mi = 0; mi < 8; ++mi) {
            const int mb = m0 + wm + mi * 16 + crow;
#pragma unroll
            for (int r = 0; r < 4; ++r)
                C[(size_t)(mb + r) * N + n] = acc[mi][ni][r] + bv;
        }
    }
}

// ---------------------------------------------------------------------------
extern "C" void kernel_launch(void* const* d_in, const int* in_sizes, int n_in,
                              void* d_out, int out_size, void* d_ws, size_t ws_size,
                              hipStream_t stream) {
    const float* x = (const float*)d_in[0];   // [B,S,K] fp32
    const float* W = (const float*)d_in[1];   // [N,K]   fp32
    const float* b = (const float*)d_in[2];   // [N]     fp32
    float* out = (float*)d_out;               // [B,S,N] fp32

    const int K = 4096;
    const int N = 4096;
    const int M = in_sizes[0] / K;            // 8192

    bf16_t* xb = (bf16_t*)d_ws;               // M*K bf16 = 64 MiB
    bf16_t* Wt = xb + (size_t)M * K;          // N*K bf16 = 32 MiB

    hipLaunchKernelGGL(fwht_rows_bf16, dim3(N), dim3(256), 0, stream, W, Wt);

    const int cvt_blocks = (int)(((size_t)M * K) / 8 / 256);  // 16384
    hipLaunchKernelGGL(cvt_f32_bf16, dim3(cvt_blocks), dim3(256), 0, stream,
                       (const float4*)x, (bf16x8*)xb);

    hipLaunchKernelGGL(gemm256_bt_bias, dim3(N / BN, M / BM), dim3(512), 0, stream,
                       xb, Wt, b, out, M, N, K);
}

// Round 2
// 492.106 us; speedup vs baseline: 1.0360x; 1.0360x over previous
//
#include <hip/hip_runtime.h>
#include <hip/hip_bf16.h>
#include <cstdint>
#include <cstddef>

typedef __bf16 bf16_t;
typedef bf16_t bf16x8 __attribute__((ext_vector_type(8)));
typedef float  f32x4  __attribute__((ext_vector_type(4)));

#define FWHT_N 4096

// ---- GEMM geometry: 256x256 tile, K-step 32, 4-deep LDS pipeline ----
#define BM 256
#define BN 256
#define KSTEP 32
#define ABYTES 16384          // 256 rows x 32 k x 2B (one step's A)
#define BUFBYTES 32768        // A + B per step-buffer
#define NBUF 4                // 4 x 32 KiB = 128 KiB LDS

// ---------------------------------------------------------------------------
// 16-point in-register FWHT (4 radix-2 stages, unnormalized)
// ---------------------------------------------------------------------------
__device__ __forceinline__ void fwht16(float v[16]) {
#pragma unroll
    for (int h = 1; h < 16; h <<= 1) {
#pragma unroll
        for (int i = 0; i < 16; ++i) {
            if (!(i & h)) {
                const float a = v[i];
                const float b = v[i | h];
                v[i]     = a + b;
                v[i | h] = a - b;
            }
        }
    }
}

// padded LDS address: +1 word every 32 => all round patterns are 2-way (free)
__device__ __forceinline__ int pad(int i) { return i + (i >> 5); }

// ---------------------------------------------------------------------------
// Kernel 1: normalized FWHT along rows of W, emit bf16 W'
// W' = H * W[o,:] / 64  (H symmetric => x@W'^T == fwht(x)@W^T)
// ---------------------------------------------------------------------------
__global__ __launch_bounds__(256) void fwht_rows_bf16(const float* __restrict__ W,
                                                      bf16_t* __restrict__ Wt) {
    __shared__ float lds[FWHT_N + (FWHT_N >> 5)];
    const int r = blockIdx.x;
    const int t = threadIdx.x;

    float v[16];

    // ---- round 0: bits 0-3, i = 16t + k (contiguous) ----
    const float4* src = (const float4*)(W + (size_t)r * FWHT_N + 16 * t);
    {
        const float4 a0 = src[0], a1 = src[1], a2 = src[2], a3 = src[3];
        v[0] = a0.x; v[1] = a0.y; v[2]  = a0.z; v[3]  = a0.w;
        v[4] = a1.x; v[5] = a1.y; v[6]  = a1.z; v[7]  = a1.w;
        v[8] = a2.x; v[9] = a2.y; v[10] = a2.z; v[11] = a2.w;
        v[12] = a3.x; v[13] = a3.y; v[14] = a3.z; v[15] = a3.w;
    }
    fwht16(v);
    {
        const int base = 16 * t + (t >> 1);
#pragma unroll
        for (int k = 0; k < 16; ++k) lds[base + k] = v[k];
    }
    __syncthreads();

    // ---- round 1: bits 4-7 ----
    const int b1 = ((t >> 4) << 8) | (t & 15);
#pragma unroll
    for (int k = 0; k < 16; ++k) v[k] = lds[pad(b1 + (k << 4))];
    fwht16(v);
#pragma unroll
    for (int k = 0; k < 16; ++k) lds[pad(b1 + (k << 4))] = v[k];
    __syncthreads();

    // ---- round 2: bits 8-11 ----
#pragma unroll
    for (int k = 0; k < 16; ++k) v[k] = lds[pad(t + (k << 8))];
    fwht16(v);

    const float s = 0.015625f;  // 1/sqrt(4096)
    bf16_t* dst = Wt + (size_t)r * FWHT_N + t;
#pragma unroll
    for (int k = 0; k < 16; ++k) dst[k << 8] = (bf16_t)(v[k] * s);
}

// ---------------------------------------------------------------------------
// Kernel 2: x fp32 -> bf16, 16B/lane stores
// ---------------------------------------------------------------------------
__global__ __launch_bounds__(256) void cvt_f32_bf16(const float4* __restrict__ x,
                                                    bf16x8* __restrict__ y) {
    const size_t i = (size_t)blockIdx.x * 256 + threadIdx.x;
    const float4 a = x[2 * i];
    const float4 b = x[2 * i + 1];
    bf16x8 o;
    o[0] = (bf16_t)a.x; o[1] = (bf16_t)a.y; o[2] = (bf16_t)a.z; o[3] = (bf16_t)a.w;
    o[4] = (bf16_t)b.x; o[5] = (bf16_t)b.y; o[6] = (bf16_t)b.z; o[7] = (bf16_t)b.w;
    y[i] = o;
}

// ---------------------------------------------------------------------------
// Kernel 3: C[M,N] = A[M,K] * B[N,K]^T + bias   (bf16 in, fp32 out)
// 256x256 tile, 8 waves (2Mx4N), KSTEP=32, 4-deep rotating LDS pipeline.
// Round-2 additions:
//   - register double-buffered fragments: ds_read frags(s+1) issues under
//     MFMA(frags s) with compiler-counted lgkmcnt (no per-step LDS stall)
//   - bijective XCD-chunked block swizzle (512 % 8 == 0)
// Schedule per half-iteration s:
//   vmcnt(4)  -> retires tile s+1's 4 global_load_lds (keeps tile s+2 in flight)
//   s_barrier + sched_barrier(0)
//   ds_read frags(s+1) [12 x b128, alt reg set]
//   stage(s+3)         [4 x global_load_lds -> buf (s+3)&3 == buf (s-1)&3,
//                       whose readers drained at MFMA(s-1), pre-barrier]
//   MFMA(frags s) x32 under setprio(1)
// ---------------------------------------------------------------------------
__device__ __forceinline__ void g2lds16(const bf16_t* g, bf16_t* l) {
    __builtin_amdgcn_global_load_lds((__attribute__((address_space(1))) void*)g,
                                     (__attribute__((address_space(3))) void*)l,
                                     16, 0, 0);
}

__global__ __launch_bounds__(512, 2) void gemm256_bt_bias(
    const bf16_t* __restrict__ A,
    const bf16_t* __restrict__ Bm,
    const float* __restrict__ bias,
    float* __restrict__ C,
    int M, int N, int K)
{
    __shared__ __align__(16) char lds[NBUF * BUFBYTES];  // 128 KiB

    const int tid  = threadIdx.x;
    const int wave = tid >> 6;
    const int lane = tid & 63;
    const int quad = lane >> 4;
    const int l16  = lane & 15;

    // ---- bijective XCD-chunked swizzle (nwg = 512, % 8 == 0) ----
    const int nbx  = N / BN;                                  // 16
    const int flat = blockIdx.y * nbx + blockIdx.x;
    const int per  = (nbx * (M / BM)) >> 3;                   // 64
    const int nf   = (flat & 7) * per + (flat >> 3);
    const int m0   = (nf / nbx) * BM;
    const int n0   = (nf % nbx) * BN;

    const int wm = (wave >> 2) * 128;   // 2 M-warps
    const int wn = (wave & 3) * 64;     // 4 N-warps

    // ---- staging map: linear LDS dest <- inverse-swizzled global source ----
    const int srow = wave * 16 + (lane >> 2);                      // 0..127
    const int scb  = (((lane & 3) ^ ((lane >> 3) & 3)) << 4);      // bytes in 64B k-run
    const int L0   = wave * 1024 + lane * 16;                      // linear LDS bytes

    const bf16_t* gA0 = A  + (size_t)(m0 + srow)       * K + (scb >> 1);
    const bf16_t* gA1 = A  + (size_t)(m0 + srow + 128) * K + (scb >> 1);
    const bf16_t* gB0 = Bm + (size_t)(n0 + srow)       * K + (scb >> 1);
    const bf16_t* gB1 = Bm + (size_t)(n0 + srow + 128) * K + (scb >> 1);

    // ---- ds_read fragment addresses (same swizzle on the read side) ----
    const int cbr   = ((quad ^ ((lane >> 1) & 3)) << 4);
    const int aoff  = l16 * 64 + cbr;
    const int abase = ((wm >> 4) << 10) + aoff;            // + mi*1024
    const int bbase = ABYTES + ((wn >> 4) << 10) + aoff;   // + ni*1024

    f32x4 acc[8][4] = {};
    bf16x8 aF0[8], bF0[4], aF1[8], bF1[4];

    const int NT = K / KSTEP;  // 128

    auto stageTo = [&](int s) {
        char* d = &lds[(s & (NBUF - 1)) * BUFBYTES];
        const int ko = (s < NT ? s : NT - 1) * KSTEP;   // clamped: keeps vmcnt constant
        g2lds16(gA0 + ko, (bf16_t*)(d + L0));
        g2lds16(gA1 + ko, (bf16_t*)(d + L0 + 8192));
        g2lds16(gB0 + ko, (bf16_t*)(d + ABYTES + L0));
        g2lds16(gB1 + ko, (bf16_t*)(d + ABYTES + L0 + 8192));
    };
    auto loadFrags = [&](int s, bf16x8 (&fa)[8], bf16x8 (&fb)[4]) {
        const int sc = (s < NT ? s : NT - 1);
        const char* buf = &lds[(sc & (NBUF - 1)) * BUFBYTES];
#pragma unroll
        for (int ni = 0; ni < 4; ++ni)
            fb[ni] = *(const bf16x8*)(buf + bbase + (ni << 10));
#pragma unroll
        for (int mi = 0; mi < 8; ++mi)
            fa[mi] = *(const bf16x8*)(buf + abase + (mi << 10));
    };
    auto mfmaAll = [&](bf16x8 (&fa)[8], bf16x8 (&fb)[4]) {
        __builtin_amdgcn_s_setprio(1);
#pragma unroll
        for (int mi = 0; mi < 8; ++mi)
#pragma unroll
            for (int ni = 0; ni < 4; ++ni)
                acc[mi][ni] = __builtin_amdgcn_mfma_f32_16x16x32_bf16(
                    fa[mi], fb[ni], acc[mi][ni], 0, 0, 0);
        __builtin_amdgcn_s_setprio(0);
    };

    // ---- prologue: tiles 0,1 in flight; retire 0; frags(0) -> set0; issue 2 ----
    stageTo(0);
    stageTo(1);
    asm volatile("s_waitcnt vmcnt(4)" ::: "memory");
    __builtin_amdgcn_s_barrier();
    __builtin_amdgcn_sched_barrier(0);
    loadFrags(0, aF0, bF0);
    stageTo(2);

#pragma unroll 1
    for (int s = 0; s < NT; s += 2) {
        // half-iter s: consume set0, prefetch into set1
        asm volatile("s_waitcnt vmcnt(4)" ::: "memory");   // tile s+1 landed
        __builtin_amdgcn_s_barrier();
        __builtin_amdgcn_sched_barrier(0);
        loadFrags(s + 1, aF1, bF1);
        stageTo(s + 3);
        mfmaAll(aF0, bF0);

        // half-iter s+1: consume set1, prefetch into set0
        asm volatile("s_waitcnt vmcnt(4)" ::: "memory");   // tile s+2 landed
        __builtin_amdgcn_s_barrier();
        __builtin_amdgcn_sched_barrier(0);
        loadFrags(s + 2, aF0, bF0);
        stageTo(s + 4);
        mfmaAll(aF1, bF1);
    }
    asm volatile("s_waitcnt vmcnt(0)" ::: "memory");       // drain dangling stages

    // ---- epilogue: C = acc + bias (C/D map: col=lane&15, row=quad*4+r) ----
    const int crow = quad * 4;
#pragma unroll
    for (int ni = 0; ni < 4; ++ni) {
        const int n  = n0 + wn + ni * 16 + l16;
        const float bv = bias[n];
#pragma unroll
        for (int mi = 0; mi < 8; ++mi) {
            const int mb = m0 + wm + mi * 16 + crow;
#pragma unroll
            for (int r = 0; r < 4; ++r)
                C[(size_t)(mb + r) * N + n] = acc[mi][ni][r] + bv;
        }
    }
}

// ---------------------------------------------------------------------------
extern "C" void kernel_launch(void* const* d_in, const int* in_sizes, int n_in,
                              void* d_out, int out_size, void* d_ws, size_t ws_size,
                              hipStream_t stream) {
    const float* x = (const float*)d_in[0];   // [B,S,K] fp32
    const float* W = (const float*)d_in[1];   // [N,K]   fp32
    const float* b = (const float*)d_in[2];   // [N]     fp32
    float* out = (float*)d_out;               // [B,S,N] fp32

    const int K = 4096;
    const int N = 4096;
    const int M = in_sizes[0] / K;            // 8192

    bf16_t* xb = (bf16_t*)d_ws;               // M*K bf16 = 64 MiB
    bf16_t* Wt = xb + (size_t)M * K;          // N*K bf16 = 32 MiB

    hipLaunchKernelGGL(fwht_rows_bf16, dim3(N), dim3(256), 0, stream, W, Wt);

    const int cvt_blocks = (int)(((size_t)M * K) / 8 / 256);  // 16384
    hipLaunchKernelGGL(cvt_f32_bf16, dim3(cvt_blocks), dim3(256), 0, stream,
                       (const float4*)x, (bf16x8*)xb);

    hipLaunchKernelGGL(gemm256_bt_bias, dim3(N / BN, M / BM), dim3(512), 0, stream,
                       xb, Wt, b, out, M, N, K);
}